// Round 1
// baseline (924.647 us; speedup 1.0000x reference)
//
#include <hip/hip_runtime.h>
#include <cstddef>

#define Bb 16
#define Uu 2048
#define Dd 512
#define BU (Bb*Uu)

// ---------------- Kernel 1: transpose conv_w (D,D,3) -> Wt (3,D,D) [tap][i][d]
__global__ __launch_bounds__(256) void transpose_w_kernel(const float* __restrict__ conv_w,
                                                          float* __restrict__ Wt) {
  int idx = blockIdx.x * 256 + threadIdx.x;          // < 3*D*D
  int tap = idx / (Dd * Dd);
  int rem = idx - tap * Dd * Dd;
  int i = rem >> 9;
  int d = rem & 511;
  Wt[idx] = conv_w[((size_t)d * Dd + i) * 3 + tap];
}

// ---------------- Kernel 2: fused conv-GEMM + ReLU + lin_w partial dot
// grid (8 d-tiles, 512 frame-tiles), block 256. Writes partial[dt][b*U+u].
__global__ __launch_bounds__(256) void conv_gemm_kernel(
    const float* __restrict__ xs, const float* __restrict__ Wt,
    const float* __restrict__ conv_b, const float* __restrict__ lin_w,
    float* __restrict__ partial)
{
  __shared__ __align__(16) float AsT[32][68];   // [kk][frame]
  __shared__ __align__(16) float Bs[32][68];    // [kk][d]
  const int dt = blockIdx.x;
  const int ft = blockIdx.y;
  const int b  = ft >> 5;
  const int u0 = (ft & 31) << 6;
  const int d0 = dt << 6;
  const int tid = threadIdx.x;
  const int tx = tid & 15, ty = tid >> 4;

  float acc[4][4] = {};
  const float* xsb = xs + (size_t)b * (Uu * Dd);

  const int acol = tid & 31, ar0 = tid >> 5;    // A loader: channel, row base
  const int bcol = tid & 63, br0 = tid >> 6;    // B loader: d, row base

  for (int tap = 0; tap < 3; ++tap) {
    for (int c = 0; c < Dd; c += 32) {
      // A tile: row r holds xs[u0 + tap - 1 + r][c..c+31], transposed into AsT
      #pragma unroll
      for (int l = 0; l < 8; ++l) {
        int r = ar0 + (l << 3);
        int uu = u0 + tap - 1 + r;
        float v = 0.f;
        if (uu >= 0 && uu < Uu) v = xsb[(size_t)uu * Dd + (c + acol)];
        AsT[acol][r] = v;
      }
      // B tile: Wt[tap][c+r][d0+bcol]
      #pragma unroll
      for (int l = 0; l < 8; ++l) {
        int r = br0 + (l << 2);
        Bs[r][bcol] = Wt[((size_t)tap * Dd + (c + r)) * Dd + (d0 + bcol)];
      }
      __syncthreads();
      #pragma unroll
      for (int kk = 0; kk < 32; ++kk) {
        float4 av = *reinterpret_cast<const float4*>(&AsT[kk][ty << 2]);
        float4 bv = *reinterpret_cast<const float4*>(&Bs[kk][tx << 2]);
        acc[0][0] += av.x*bv.x; acc[0][1] += av.x*bv.y; acc[0][2] += av.x*bv.z; acc[0][3] += av.x*bv.w;
        acc[1][0] += av.y*bv.x; acc[1][1] += av.y*bv.y; acc[1][2] += av.y*bv.z; acc[1][3] += av.y*bv.w;
        acc[2][0] += av.z*bv.x; acc[2][1] += av.z*bv.y; acc[2][2] += av.z*bv.z; acc[2][3] += av.z*bv.w;
        acc[3][0] += av.w*bv.x; acc[3][1] += av.w*bv.y; acc[3][2] += av.w*bv.z; acc[3][3] += av.w*bv.w;
      }
      __syncthreads();
    }
  }
  // epilogue: relu(h + conv_b) * lin_w, reduce over this tile's 64 channels
  float p0 = 0.f, p1 = 0.f, p2 = 0.f, p3 = 0.f;
  #pragma unroll
  for (int j = 0; j < 4; ++j) {
    int d = d0 + (tx << 2) + j;
    float cb = conv_b[d], lw = lin_w[d];
    float h0 = acc[0][j] + cb; h0 = h0 > 0.f ? h0 : 0.f; p0 += h0 * lw;
    float h1 = acc[1][j] + cb; h1 = h1 > 0.f ? h1 : 0.f; p1 += h1 * lw;
    float h2 = acc[2][j] + cb; h2 = h2 > 0.f ? h2 : 0.f; p2 += h2 * lw;
    float h3 = acc[3][j] + cb; h3 = h3 > 0.f ? h3 : 0.f; p3 += h3 * lw;
  }
  #pragma unroll
  for (int m = 1; m < 16; m <<= 1) {
    p0 += __shfl_xor(p0, m);
    p1 += __shfl_xor(p1, m);
    p2 += __shfl_xor(p2, m);
    p3 += __shfl_xor(p3, m);
  }
  if (tx == 0) {
    float* pp = partial + (size_t)dt * BU + (size_t)b * Uu + u0 + (ty << 2);
    pp[0] = p0; pp[1] = p1; pp[2] = p2; pp[3] = p3;
  }
}

// ---------------- Kernel 3: alpha = mask * sigmoid(sum partials + lin_b); per-64-chunk sums
__global__ __launch_bounds__(256) void alpha_kernel(
    const float* __restrict__ partial, const float* __restrict__ lin_b,
    const int* __restrict__ xlens,
    float* __restrict__ alpha, float* __restrict__ psums)
{
  int idx = blockIdx.x * 256 + threadIdx.x;
  int b = idx >> 11;
  int u = idx & 2047;
  float v = lin_b[0];
  #pragma unroll
  for (int dt = 0; dt < 8; ++dt) v += partial[(size_t)dt * BU + idx];
  float a = 1.f / (1.f + expf(-v));
  if (u >= xlens[b]) a = 0.f;
  alpha[idx] = a;
  float s = a;
  #pragma unroll
  for (int m = 1; m < 64; m <<= 1) s += __shfl_xor(s, m);
  if ((threadIdx.x & 63) == 0) psums[(b << 5) + (u >> 6)] = s;
}

// ---------------- Kernel 4: sequential faithful scan (one wave per batch)
__global__ __launch_bounds__(64) void scan_kernel(
    const float* __restrict__ alpha, const float* __restrict__ psums,
    const int* __restrict__ xlens, const int* __restrict__ ylens,
    float* __restrict__ wA, float* __restrict__ wB,
    int* __restrict__ fire_pos, int* __restrict__ nf,
    float* __restrict__ out_sum)
{
  int b = blockIdx.x;
  int lane = threadIdx.x;
  float ps = (lane < 32) ? psums[(b << 5) + lane] : 0.f;
  #pragma unroll
  for (int m = 1; m < 32; m <<= 1) ps += __shfl_xor(ps, m);
  float sa = __shfl(ps, 0);
  float beta = sa / (float)ylens[b] - 1e-4f;
  int xl = xlens[b];
  if (lane == 0) out_sum[b] = sa;

  const float* ab = alpha + (size_t)b * Uu;
  float prev = 0.f;
  int cnt = 0;
  for (int u0 = 0; u0 < Uu; u0 += 64) {
    if (u0 >= xl) break;                 // alpha==0 beyond xl: no fires, weights unread
    float val = ab[u0 + lane];
    float mywa = 0.f, mywb = 0.f;
    float a_cur = __shfl(val, 0);
    #pragma unroll 4
    for (int i = 0; i < 64; ++i) {
      float a_next = __shfl(val, (i + 1) & 63);   // prefetch, hides bpermute latency
      float nw = prev + a_cur;                    // exact reference rounding order
      float left = beta - prev;
      float right = nw - beta;
      bool fired = nw >= beta;
      if (lane == i) { mywa = left; mywb = right; }
      if (fired) {
        if (lane == 0) fire_pos[(b << 11) + cnt] = u0 + i;
        ++cnt;
      }
      prev = fired ? right : nw;
      a_cur = a_next;
    }
    wA[(size_t)b * Uu + u0 + lane] = mywa;
    wB[(size_t)b * Uu + u0 + lane] = mywb;
  }
  if (lane == 0) nf[b] = cnt;
}

// ---------------- Kernel 5: segmented gather -> h_cif
__global__ __launch_bounds__(512) void gather_kernel(
    const float* __restrict__ xs, const float* __restrict__ wA, const float* __restrict__ wB,
    const int* __restrict__ fire_pos, const int* __restrict__ nf,
    float* __restrict__ out, int umax)
{
  int t = blockIdx.x, b = blockIdx.y;
  int tid = threadIdx.x;
  float* o = out + ((size_t)b * umax + t) * Dd;
  int n = nf[b];
  if (t >= n) { o[tid] = 0.f; return; }
  int start = (t == 0) ? 0 : fire_pos[(b << 11) + t - 1];
  int end = fire_pos[(b << 11) + t];
  const float* xb = xs + (size_t)b * Uu * Dd;
  float acc = 0.f;
  for (int u = start; u <= end; ++u) {
    float w = (t > 0 && u == start) ? wB[(size_t)b * Uu + u] : wA[(size_t)b * Uu + u];
    acc += w * xb[(size_t)u * Dd + tid];
  }
  o[tid] = acc;
}

extern "C" void kernel_launch(void* const* d_in, const int* in_sizes, int n_in,
                              void* d_out, int out_size, void* d_ws, size_t ws_size,
                              hipStream_t stream) {
  const float* xs     = (const float*)d_in[0];
  const int*   xlens  = (const int*)d_in[1];
  const int*   ylens  = (const int*)d_in[2];
  const float* conv_w = (const float*)d_in[3];
  const float* conv_b = (const float*)d_in[4];
  const float* lin_w  = (const float*)d_in[5];
  const float* lin_b  = (const float*)d_in[6];
  float* out = (float*)d_out;
  int umax = (out_size - Bb) / (Bb * Dd);

  char* ws = (char*)d_ws;
  float* Wt       = (float*)ws;                         // 3*D*D*4   = 3 MB
  float* partial  = (float*)(ws + 3 * Dd * Dd * 4);     // 8*BU*4    = 1 MB
  float* alpha    = partial + 8 * BU;                   // BU*4
  float* wAv      = alpha + BU;                         // BU*4
  float* wBv      = wAv + BU;                           // BU*4
  int*   fire_pos = (int*)(wBv + BU);                   // BU*4
  float* psums    = (float*)(fire_pos + BU);            // 512*4
  int*   nf       = (int*)(psums + Bb * 32);            // 16*4

  transpose_w_kernel<<<(3 * Dd * Dd) / 256, 256, 0, stream>>>(conv_w, Wt);
  conv_gemm_kernel<<<dim3(8, BU / 64), 256, 0, stream>>>(xs, Wt, conv_b, lin_w, partial);
  alpha_kernel<<<BU / 256, 256, 0, stream>>>(partial, lin_b, xlens, alpha, psums);
  scan_kernel<<<Bb, 64, 0, stream>>>(alpha, psums, xlens, ylens, wAv, wBv, fire_pos, nf,
                                     out + (size_t)Bb * umax * Dd);
  if (umax > 0)
    gather_kernel<<<dim3(umax, Bb), 512, 0, stream>>>(xs, wAv, wBv, fire_pos, nf, out, umax);
}

// Round 2
// 401.847 us; speedup vs baseline: 2.3010x; 2.3010x over previous
//
#include <hip/hip_runtime.h>
#include <cstddef>
#include <cstdint>

#define Bb 16
#define Uu 2048
#define Dd 512
#define BU (Bb*Uu)

typedef short bf16x8 __attribute__((ext_vector_type(8)));
typedef float f32x4 __attribute__((ext_vector_type(4)));

#define ROW_BYTES 208            // 96 bf16 payload (h32,m32,l32) + 16B pad; 52 dwords -> 2-way-max banks
#define A_ROWS 130
#define B_OFF 27648              // A region padded to here (130*208 = 27040)
#define STEP_BYTES (512*ROW_BYTES)   // 106496 per (chunk,tap) B block
#define SMEM_BYTES (B_OFF + STEP_BYTES)

__device__ __forceinline__ unsigned short f2bf(float x){
  unsigned int u = __float_as_uint(x);
  u += 0x7fff + ((u >> 16) & 1);          // RNE
  return (unsigned short)(u >> 16);
}
__device__ __forceinline__ float bf2f(unsigned short b){
  return __uint_as_float(((unsigned int)b) << 16);
}

union U16x8 { unsigned short s[8]; uint4 v; };

__device__ __forceinline__ void split3(float x, unsigned short& h, unsigned short& m, unsigned short& l){
  h = f2bf(x);
  float r1 = x - bf2f(h);
  m = f2bf(r1);
  float r2 = r1 - bf2f(m);
  l = f2bf(r2);
}

// ---------------- pack conv_w -> Bpack[step=(chunk*3+tap)][n(512)][208B: bh32|bm32|bl32|pad]
__global__ __launch_bounds__(256) void pack_b_kernel(const float* __restrict__ conv_w,
                                                     char* __restrict__ Bpack){
  int idx = blockIdx.x * 256 + threadIdx.x;    // < 48*2048
  int step = idx >> 11;
  int rem = idx & 2047;
  int n = rem >> 2, u = rem & 3;
  int chunk = step / 3, tap = step - chunk * 3;
  int c0 = chunk * 32 + u * 8;
  U16x8 H, M, L;
  #pragma unroll
  for (int j = 0; j < 8; ++j){
    float w = conv_w[((size_t)n * Dd + (c0 + j)) * 3 + tap];
    split3(w, H.s[j], M.s[j], L.s[j]);
  }
  char* dst = Bpack + (size_t)step * STEP_BYTES + n * ROW_BYTES + u * 16;
  *(uint4*)(dst)       = H.v;
  *(uint4*)(dst + 64)  = M.v;
  *(uint4*)(dst + 128) = L.v;
}

// ---------------- conv GEMM via split-bf16 MFMA, fused alpha epilogue
__device__ __forceinline__ void stage_A(char* smem, const float* __restrict__ xsb,
                                        int u0, int c0, int tid){
  #pragma unroll
  for (int it = 0; it < 2; ++it){
    if (it == 0 || tid < 8){
      int t = tid + it * 512;                 // 520 tasks: 130 rows x 4 col-groups
      int r = t >> 2, cg = t & 3;
      int uu = u0 - 1 + r;
      float x[8];
      if (uu >= 0 && uu < Uu){
        const float* p = xsb + (size_t)uu * Dd + c0 + cg * 8;
        float4 a = *(const float4*)p;
        float4 b = *(const float4*)(p + 4);
        x[0]=a.x; x[1]=a.y; x[2]=a.z; x[3]=a.w; x[4]=b.x; x[5]=b.y; x[6]=b.z; x[7]=b.w;
      } else {
        #pragma unroll
        for (int j = 0; j < 8; ++j) x[j] = 0.f;
      }
      U16x8 H, M, L;
      #pragma unroll
      for (int j = 0; j < 8; ++j) split3(x[j], H.s[j], M.s[j], L.s[j]);
      char* dst = smem + r * ROW_BYTES + cg * 16;
      *(uint4*)(dst)       = H.v;
      *(uint4*)(dst + 64)  = M.v;
      *(uint4*)(dst + 128) = L.v;
    }
  }
}

__device__ __forceinline__ void stage_B(char* smem, const char* __restrict__ bsrc, int tid){
  int wv = tid >> 6, ln = tid & 63;
  const char* g = bsrc + wv * 13312 + ln * 16;
  char* l = smem + B_OFF + wv * 13312;        // wave-uniform LDS base; HW adds lane*16
  #pragma unroll
  for (int i = 0; i < 13; ++i){
    __builtin_amdgcn_global_load_lds(
        (const __attribute__((address_space(1))) unsigned int*)(g + i * 1024),
        (__attribute__((address_space(3))) unsigned int*)(l + i * 1024), 16, 0, 0);
  }
}

__device__ __forceinline__ bf16x8 ldfrag(const char* p){
  return __builtin_bit_cast(bf16x8, *(const uint4*)p);
}

__device__ __forceinline__ void compute_tap(const char* smem, f32x4 (&acc)[4][8],
                                            int wm, int wn, int lane, int tap){
  const int li = lane & 15, lg = lane >> 4;
  bf16x8 a[4][3];
  #pragma unroll
  for (int m = 0; m < 4; ++m){
    const char* ar = smem + (size_t)(wm * 64 + m * 16 + li + tap) * ROW_BYTES + lg * 16;
    a[m][0] = ldfrag(ar);
    a[m][1] = ldfrag(ar + 64);
    a[m][2] = ldfrag(ar + 128);
  }
  #pragma unroll
  for (int n = 0; n < 8; ++n){
    const char* br = smem + B_OFF + (size_t)(wn * 128 + n * 16 + li) * ROW_BYTES + lg * 16;
    bf16x8 bh = ldfrag(br);
    bf16x8 bm = ldfrag(br + 64);
    bf16x8 bl = ldfrag(br + 128);
    #pragma unroll
    for (int m = 0; m < 4; ++m){
      acc[m][n] = __builtin_amdgcn_mfma_f32_16x16x32_bf16(a[m][0], bh, acc[m][n], 0, 0, 0); // hh
      acc[m][n] = __builtin_amdgcn_mfma_f32_16x16x32_bf16(a[m][1], bh, acc[m][n], 0, 0, 0); // mh
      acc[m][n] = __builtin_amdgcn_mfma_f32_16x16x32_bf16(a[m][0], bm, acc[m][n], 0, 0, 0); // hm
      acc[m][n] = __builtin_amdgcn_mfma_f32_16x16x32_bf16(a[m][0], bl, acc[m][n], 0, 0, 0); // hl
      acc[m][n] = __builtin_amdgcn_mfma_f32_16x16x32_bf16(a[m][2], bh, acc[m][n], 0, 0, 0); // lh
      acc[m][n] = __builtin_amdgcn_mfma_f32_16x16x32_bf16(a[m][1], bm, acc[m][n], 0, 0, 0); // mm
    }
  }
}

__global__ __launch_bounds__(512, 2) void conv_mfma_kernel(
    const float* __restrict__ xs, const char* __restrict__ Bpack,
    const float* __restrict__ conv_b, const float* __restrict__ lin_w,
    const float* __restrict__ lin_b, const int* __restrict__ xlens,
    float* __restrict__ alpha, float* __restrict__ psums)
{
  __shared__ __align__(16) char smem[SMEM_BYTES];
  const int tid = threadIdx.x;
  const int lane = tid & 63, wv = tid >> 6;
  const int wm = wv >> 2, wn = wv & 3;
  const int blk = blockIdx.x;
  const int b = blk >> 4, ut = blk & 15;
  const int u0 = ut * 128;
  const float* xsb = xs + (size_t)b * Uu * Dd;

  f32x4 acc[4][8];
  #pragma unroll
  for (int m = 0; m < 4; ++m)
    #pragma unroll
    for (int n = 0; n < 8; ++n){
      f32x4 z = {0.f, 0.f, 0.f, 0.f};
      acc[m][n] = z;
    }

  for (int chunk = 0; chunk < 16; ++chunk){
    __syncthreads();                                  // prev compute done
    stage_A(smem, xsb, u0, chunk * 32, tid);
    stage_B(smem, Bpack + (size_t)(chunk * 3 + 0) * STEP_BYTES, tid);
    __syncthreads();
    compute_tap(smem, acc, wm, wn, lane, 0);
    __syncthreads();
    stage_B(smem, Bpack + (size_t)(chunk * 3 + 1) * STEP_BYTES, tid);
    __syncthreads();
    compute_tap(smem, acc, wm, wn, lane, 1);
    __syncthreads();
    stage_B(smem, Bpack + (size_t)(chunk * 3 + 2) * STEP_BYTES, tid);
    __syncthreads();
    compute_tap(smem, acc, wm, wn, lane, 2);
  }

  // ---- fused epilogue: relu(h+conv_b)*lin_w, reduce over channels -> alpha + psums
  __syncthreads();
  float* pbuf = (float*)smem;                         // [128 frames][4 wn]
  const int li = lane & 15, lg = lane >> 4;
  #pragma unroll
  for (int m = 0; m < 4; ++m){
    float s0 = 0.f, s1 = 0.f, s2 = 0.f, s3 = 0.f;
    #pragma unroll
    for (int n = 0; n < 8; ++n){
      int col = wn * 128 + n * 16 + li;
      float cb = conv_b[col], lw = lin_w[col];
      f32x4 v = acc[m][n];
      float h;
      h = v[0] + cb; h = h > 0.f ? h : 0.f; s0 += h * lw;
      h = v[1] + cb; h = h > 0.f ? h : 0.f; s1 += h * lw;
      h = v[2] + cb; h = h > 0.f ? h : 0.f; s2 += h * lw;
      h = v[3] + cb; h = h > 0.f ? h : 0.f; s3 += h * lw;
    }
    #pragma unroll
    for (int msk = 1; msk < 16; msk <<= 1){
      s0 += __shfl_xor(s0, msk); s1 += __shfl_xor(s1, msk);
      s2 += __shfl_xor(s2, msk); s3 += __shfl_xor(s3, msk);
    }
    if (li == 0){
      int fr = wm * 64 + m * 16 + lg * 4;
      pbuf[(fr + 0) * 4 + wn] = s0;
      pbuf[(fr + 1) * 4 + wn] = s1;
      pbuf[(fr + 2) * 4 + wn] = s2;
      pbuf[(fr + 3) * 4 + wn] = s3;
    }
  }
  __syncthreads();
  if (tid < 128){
    float p = pbuf[tid*4] + pbuf[tid*4+1] + pbuf[tid*4+2] + pbuf[tid*4+3] + lin_b[0];
    float a = 1.f / (1.f + expf(-p));
    int u = u0 + tid;
    if (u >= xlens[b]) a = 0.f;
    alpha[(size_t)b * Uu + u] = a;
    float s = a;
    #pragma unroll
    for (int msk = 1; msk < 64; msk <<= 1) s += __shfl_xor(s, msk);
    if (lane == 0) psums[(b << 5) + (u >> 6)] = s;
  }
}

// ---------------- sequential faithful scan (one wave per batch) — unchanged (passed R1)
__global__ __launch_bounds__(64) void scan_kernel(
    const float* __restrict__ alpha, const float* __restrict__ psums,
    const int* __restrict__ xlens, const int* __restrict__ ylens,
    float* __restrict__ wA, float* __restrict__ wB,
    int* __restrict__ fire_pos, int* __restrict__ nf,
    float* __restrict__ out_sum)
{
  int b = blockIdx.x;
  int lane = threadIdx.x;
  float ps = (lane < 32) ? psums[(b << 5) + lane] : 0.f;
  #pragma unroll
  for (int m = 1; m < 32; m <<= 1) ps += __shfl_xor(ps, m);
  float sa = __shfl(ps, 0);
  float beta = sa / (float)ylens[b] - 1e-4f;
  int xl = xlens[b];
  if (lane == 0) out_sum[b] = sa;

  const float* ab = alpha + (size_t)b * Uu;
  float prev = 0.f;
  int cnt = 0;
  for (int u0 = 0; u0 < Uu; u0 += 64) {
    if (u0 >= xl) break;
    float val = ab[u0 + lane];
    float mywa = 0.f, mywb = 0.f;
    float a_cur = __shfl(val, 0);
    #pragma unroll 4
    for (int i = 0; i < 64; ++i) {
      float a_next = __shfl(val, (i + 1) & 63);
      float nw = prev + a_cur;
      float left = beta - prev;
      float right = nw - beta;
      bool fired = nw >= beta;
      if (lane == i) { mywa = left; mywb = right; }
      if (fired) {
        if (lane == 0) fire_pos[(b << 11) + cnt] = u0 + i;
        ++cnt;
      }
      prev = fired ? right : nw;
      a_cur = a_next;
    }
    wA[(size_t)b * Uu + u0 + lane] = mywa;
    wB[(size_t)b * Uu + u0 + lane] = mywb;
  }
  if (lane == 0) nf[b] = cnt;
}

// ---------------- segmented gather -> h_cif — unchanged (passed R1)
__global__ __launch_bounds__(512) void gather_kernel(
    const float* __restrict__ xs, const float* __restrict__ wA, const float* __restrict__ wB,
    const int* __restrict__ fire_pos, const int* __restrict__ nf,
    float* __restrict__ out, int umax)
{
  int t = blockIdx.x, b = blockIdx.y;
  int tid = threadIdx.x;
  float* o = out + ((size_t)b * umax + t) * Dd;
  int n = nf[b];
  if (t >= n) { o[tid] = 0.f; return; }
  int start = (t == 0) ? 0 : fire_pos[(b << 11) + t - 1];
  int end = fire_pos[(b << 11) + t];
  const float* xb = xs + (size_t)b * Uu * Dd;
  float acc = 0.f;
  for (int u = start; u <= end; ++u) {
    float w = (t > 0 && u == start) ? wB[(size_t)b * Uu + u] : wA[(size_t)b * Uu + u];
    acc += w * xb[(size_t)u * Dd + tid];
  }
  o[tid] = acc;
}

extern "C" void kernel_launch(void* const* d_in, const int* in_sizes, int n_in,
                              void* d_out, int out_size, void* d_ws, size_t ws_size,
                              hipStream_t stream) {
  const float* xs     = (const float*)d_in[0];
  const int*   xlens  = (const int*)d_in[1];
  const int*   ylens  = (const int*)d_in[2];
  const float* conv_w = (const float*)d_in[3];
  const float* conv_b = (const float*)d_in[4];
  const float* lin_w  = (const float*)d_in[5];
  const float* lin_b  = (const float*)d_in[6];
  float* out = (float*)d_out;
  int umax = (out_size - Bb) / (Bb * Dd);

  char* ws = (char*)d_ws;
  char*  Bpack    = ws;                                  // 48*106496 = 5,111,808
  float* alpha    = (float*)(ws + 48 * (size_t)STEP_BYTES);
  float* wAv      = alpha + BU;
  float* wBv      = wAv + BU;
  int*   fire_pos = (int*)(wBv + BU);
  float* psums    = (float*)(fire_pos + BU);
  int*   nf       = (int*)(psums + 512);

  pack_b_kernel<<<(48 * 2048) / 256, 256, 0, stream>>>(conv_w, Bpack);
  conv_mfma_kernel<<<256, 512, 0, stream>>>(xs, Bpack, conv_b, lin_w, lin_b, xlens,
                                            alpha, psums);
  scan_kernel<<<Bb, 64, 0, stream>>>(alpha, psums, xlens, ylens, wAv, wBv, fire_pos, nf,
                                     out + (size_t)Bb * umax * Dd);
  if (umax > 0)
    gather_kernel<<<dim3(umax, Bb), 512, 0, stream>>>(xs, wAv, wBv, fire_pos, nf, out, umax);
}

// Round 3
// 366.776 us; speedup vs baseline: 2.5210x; 1.0956x over previous
//
#include <hip/hip_runtime.h>
#include <cstddef>
#include <cstdint>

#define Bb 16
#define Uu 2048
#define Dd 512
#define BU (Bb*Uu)

typedef short bf16x8 __attribute__((ext_vector_type(8)));
typedef float f32x4 __attribute__((ext_vector_type(4)));

#define ROW_BYTES 208            // 96 bf16 payload (h32,m32,l32) + 16B pad
#define A_ROWS 130
#define B_OFF 27040              // A region: 130*208 = 27040 (16B aligned)
#define HALF_BYTES 53248         // 256 rows * 208B
#define STEP_BYTES (512*ROW_BYTES)   // 106496 per (chunk,tap) B block
#define SMEM_BYTES (B_OFF + 2*HALF_BYTES)   // 133536

__device__ __forceinline__ unsigned short f2bf(float x){
  unsigned int u = __float_as_uint(x);
  u += 0x7fff + ((u >> 16) & 1);          // RNE
  return (unsigned short)(u >> 16);
}
__device__ __forceinline__ float bf2f(unsigned short b){
  return __uint_as_float(((unsigned int)b) << 16);
}

union U16x8 { unsigned short s[8]; uint4 v; };

__device__ __forceinline__ void split3(float x, unsigned short& h, unsigned short& m, unsigned short& l){
  h = f2bf(x);
  float r1 = x - bf2f(h);
  m = f2bf(r1);
  float r2 = r1 - bf2f(m);
  l = f2bf(r2);
}

// ---------------- pack conv_w -> Bpack[step=(chunk*3+tap)][n(512)][208B: bh32|bm32|bl32|pad]
__global__ __launch_bounds__(256) void pack_b_kernel(const float* __restrict__ conv_w,
                                                     char* __restrict__ Bpack){
  int idx = blockIdx.x * 256 + threadIdx.x;    // < 48*2048
  int step = idx >> 11;
  int rem = idx & 2047;
  int n = rem >> 2, u = rem & 3;
  int chunk = step / 3, tap = step - chunk * 3;
  int c0 = chunk * 32 + u * 8;
  U16x8 H, M, L;
  #pragma unroll
  for (int j = 0; j < 8; ++j){
    float w = conv_w[((size_t)n * Dd + (c0 + j)) * 3 + tap];
    split3(w, H.s[j], M.s[j], L.s[j]);
  }
  char* dst = Bpack + (size_t)step * STEP_BYTES + n * ROW_BYTES + u * 16;
  *(uint4*)(dst)       = H.v;
  *(uint4*)(dst + 64)  = M.v;
  *(uint4*)(dst + 128) = L.v;
}

// ---------------- helpers for conv kernel
__device__ __forceinline__ void stage_A_direct(char* smem, const float* __restrict__ xsb,
                                               int u0, int c0, int tid){
  #pragma unroll
  for (int it = 0; it < 2; ++it){
    if (it == 0 || tid < 8){
      int t = tid + it * 512;                 // 520 tasks: 130 rows x 4 col-groups
      int r = t >> 2, cg = t & 3;
      int uu = u0 - 1 + r;
      float x[8];
      if (uu >= 0 && uu < Uu){
        const float* p = xsb + (size_t)uu * Dd + c0 + cg * 8;
        float4 a = *(const float4*)p;
        float4 b = *(const float4*)(p + 4);
        x[0]=a.x; x[1]=a.y; x[2]=a.z; x[3]=a.w; x[4]=b.x; x[5]=b.y; x[6]=b.z; x[7]=b.w;
      } else {
        #pragma unroll
        for (int j = 0; j < 8; ++j) x[j] = 0.f;
      }
      U16x8 H, M, L;
      #pragma unroll
      for (int j = 0; j < 8; ++j) split3(x[j], H.s[j], M.s[j], L.s[j]);
      char* dst = smem + r * ROW_BYTES + cg * 16;
      *(uint4*)(dst)       = H.v;
      *(uint4*)(dst + 64)  = M.v;
      *(uint4*)(dst + 128) = L.v;
    }
  }
}

// copy one 53248B half-tile: waves 0-3 do 7KB+..., per-lane global addr, linear LDS dest
__device__ __forceinline__ void stage_half(char* ldsB, const char* __restrict__ src,
                                           int lane, int wv){
  int base = (wv < 4) ? wv * 7168 : 28672 + (wv - 4) * 6144;
  int cnt  = (wv < 4) ? 7 : 6;
  const char* g = src + base + lane * 16;
  char* l = ldsB + base;
  for (int i = 0; i < cnt; ++i){
    __builtin_amdgcn_global_load_lds(
        (const __attribute__((address_space(1))) unsigned int*)(g + i * 1024),
        (__attribute__((address_space(3))) unsigned int*)(l + i * 1024), 16, 0, 0);
  }
}

__device__ __forceinline__ bf16x8 ldfrag(const char* p){
  return __builtin_bit_cast(bf16x8, *(const uint4*)p);
}

// ---------------- conv GEMM: 2-phase pipelined split-bf16 MFMA + fused alpha epilogue
__global__ __launch_bounds__(512, 2) void conv_mfma_kernel(
    const float* __restrict__ xs, const char* __restrict__ Bpack,
    const float* __restrict__ conv_b, const float* __restrict__ lin_w,
    const float* __restrict__ lin_b, const int* __restrict__ xlens,
    float* __restrict__ alpha, float* __restrict__ psums)
{
  __shared__ __align__(16) char smem[SMEM_BYTES];
  const int tid = threadIdx.x;
  const int lane = tid & 63, wv = tid >> 6;
  const int wm = wv >> 2, wn = wv & 3;
  const int b = blockIdx.x >> 4, ut = blockIdx.x & 15;
  const int u0 = ut * 128;
  const float* xsb = xs + (size_t)b * Uu * Dd;
  const int li = lane & 15, lg = lane >> 4;

  f32x4 acc[4][8];
  #pragma unroll
  for (int m = 0; m < 4; ++m)
    #pragma unroll
    for (int n = 0; n < 8; ++n){
      f32x4 z = {0.f, 0.f, 0.f, 0.f};
      acc[m][n] = z;
    }

  // prologue: A chunk0 (direct), B phase0 -> buf0
  stage_A_direct(smem, xsb, u0, 0, tid);
  stage_half(smem + B_OFF, Bpack, lane, wv);
  __syncthreads();

  bf16x8 a[4][3];

  for (int chunk = 0; chunk < 16; ++chunk){
    const char* stepbase = Bpack + (size_t)(chunk * 3) * STEP_BYTES;
    const bool more = (chunk < 15);
    #pragma unroll
    for (int r = 0; r < 6; ++r){
      const int tap = r >> 1, half = r & 1;
      const int buf = r & 1, nb = buf ^ 1;

      // 1. A-prefetch for next chunk (issue early; MFMA hides HBM latency)
      float4 apf0, apf1, apf2, apf3;
      int ar_ = 0, acg_ = 0;
      if (r == 5 && more){
        int c0n = (chunk + 1) * 32;
        ar_ = tid >> 2; acg_ = tid & 3;
        int uu = u0 - 1 + ar_;
        if (uu >= 0 && uu < Uu){
          const float* p = xsb + (size_t)uu * Dd + c0n + acg_ * 8;
          apf0 = *(const float4*)p;
          apf1 = *(const float4*)(p + 4);
        } else {
          apf0 = make_float4(0.f,0.f,0.f,0.f); apf1 = apf0;
        }
        apf2 = make_float4(0.f,0.f,0.f,0.f); apf3 = apf2;
        if (tid < 8){
          int t2 = 512 + tid;
          int r2 = t2 >> 2, cg2 = t2 & 3;
          int uu2 = u0 - 1 + r2;
          if (uu2 >= 0 && uu2 < Uu){
            const float* p2 = xsb + (size_t)uu2 * Dd + c0n + cg2 * 8;
            apf2 = *(const float4*)p2;
            apf3 = *(const float4*)(p2 + 4);
          }
        }
      }

      // 2. stage next phase's B half into the other buffer
      if (r < 5){
        stage_half(smem + B_OFF + nb * HALF_BYTES,
                   stepbase + ((r + 1) >> 1) * (size_t)STEP_BYTES + ((r + 1) & 1) * HALF_BYTES,
                   lane, wv);
      } else if (more){
        stage_half(smem + B_OFF + nb * HALF_BYTES,
                   Bpack + (size_t)((chunk + 1) * 3) * STEP_BYTES, lane, wv);
      }

      // 3. A fragments (shared by both halves of this tap)
      if (half == 0){
        #pragma unroll
        for (int m = 0; m < 4; ++m){
          const char* ar = smem + (size_t)(wm * 64 + m * 16 + li + tap) * ROW_BYTES + lg * 16;
          a[m][0] = ldfrag(ar);
          a[m][1] = ldfrag(ar + 64);
          a[m][2] = ldfrag(ar + 128);
        }
      }

      // 4. B fragments + MFMA (6-pass split product)
      const char* bbase = smem + B_OFF + buf * HALF_BYTES;
      #pragma unroll
      for (int n = 0; n < 4; ++n){
        const char* br = bbase + (size_t)(wn * 64 + n * 16 + li) * ROW_BYTES + lg * 16;
        bf16x8 bh = ldfrag(br);
        bf16x8 bm = ldfrag(br + 64);
        bf16x8 bl = ldfrag(br + 128);
        const int j = half * 4 + n;
        #pragma unroll
        for (int m = 0; m < 4; ++m){
          acc[m][j] = __builtin_amdgcn_mfma_f32_16x16x32_bf16(a[m][0], bh, acc[m][j], 0, 0, 0); // hh
          acc[m][j] = __builtin_amdgcn_mfma_f32_16x16x32_bf16(a[m][1], bh, acc[m][j], 0, 0, 0); // mh
          acc[m][j] = __builtin_amdgcn_mfma_f32_16x16x32_bf16(a[m][0], bm, acc[m][j], 0, 0, 0); // hm
          acc[m][j] = __builtin_amdgcn_mfma_f32_16x16x32_bf16(a[m][0], bl, acc[m][j], 0, 0, 0); // hl
          acc[m][j] = __builtin_amdgcn_mfma_f32_16x16x32_bf16(a[m][2], bh, acc[m][j], 0, 0, 0); // lh
          acc[m][j] = __builtin_amdgcn_mfma_f32_16x16x32_bf16(a[m][1], bm, acc[m][j], 0, 0, 0); // mm
        }
      }

      // 5. convert + write next chunk's A (phase-4 barrier ordered all A reads before this)
      if (r == 5 && more){
        U16x8 H, M, L;
        float x[8];
        x[0]=apf0.x; x[1]=apf0.y; x[2]=apf0.z; x[3]=apf0.w;
        x[4]=apf1.x; x[5]=apf1.y; x[6]=apf1.z; x[7]=apf1.w;
        #pragma unroll
        for (int jj = 0; jj < 8; ++jj) split3(x[jj], H.s[jj], M.s[jj], L.s[jj]);
        char* dst = smem + ar_ * ROW_BYTES + acg_ * 16;
        *(uint4*)(dst)       = H.v;
        *(uint4*)(dst + 64)  = M.v;
        *(uint4*)(dst + 128) = L.v;
        if (tid < 8){
          int t2 = 512 + tid;
          int r2 = t2 >> 2, cg2 = t2 & 3;
          float y[8];
          y[0]=apf2.x; y[1]=apf2.y; y[2]=apf2.z; y[3]=apf2.w;
          y[4]=apf3.x; y[5]=apf3.y; y[6]=apf3.z; y[7]=apf3.w;
          #pragma unroll
          for (int jj = 0; jj < 8; ++jj) split3(y[jj], H.s[jj], M.s[jj], L.s[jj]);
          char* dst2 = smem + r2 * ROW_BYTES + cg2 * 16;
          *(uint4*)(dst2)       = H.v;
          *(uint4*)(dst2 + 64)  = M.v;
          *(uint4*)(dst2 + 128) = L.v;
        }
      }
      __syncthreads();
    }
  }

  // ---- fused epilogue: relu(h+conv_b)*lin_w, reduce over channels -> alpha + psums
  float* pbuf = (float*)smem;                         // [128 frames][4 wn]
  #pragma unroll
  for (int m = 0; m < 4; ++m){
    float s0 = 0.f, s1 = 0.f, s2 = 0.f, s3 = 0.f;
    #pragma unroll
    for (int j = 0; j < 8; ++j){
      int col = (j >> 2) * 256 + wn * 64 + (j & 3) * 16 + li;
      float cb = conv_b[col], lw = lin_w[col];
      f32x4 v = acc[m][j];
      float h;
      h = v[0] + cb; h = h > 0.f ? h : 0.f; s0 += h * lw;
      h = v[1] + cb; h = h > 0.f ? h : 0.f; s1 += h * lw;
      h = v[2] + cb; h = h > 0.f ? h : 0.f; s2 += h * lw;
      h = v[3] + cb; h = h > 0.f ? h : 0.f; s3 += h * lw;
    }
    #pragma unroll
    for (int msk = 1; msk < 16; msk <<= 1){
      s0 += __shfl_xor(s0, msk); s1 += __shfl_xor(s1, msk);
      s2 += __shfl_xor(s2, msk); s3 += __shfl_xor(s3, msk);
    }
    if (li == 0){
      int fr = wm * 64 + m * 16 + lg * 4;
      pbuf[(fr + 0) * 4 + wn] = s0;
      pbuf[(fr + 1) * 4 + wn] = s1;
      pbuf[(fr + 2) * 4 + wn] = s2;
      pbuf[(fr + 3) * 4 + wn] = s3;
    }
  }
  __syncthreads();
  if (tid < 128){
    float p = pbuf[tid*4] + pbuf[tid*4+1] + pbuf[tid*4+2] + pbuf[tid*4+3] + lin_b[0];
    float a_ = 1.f / (1.f + expf(-p));
    int u = u0 + tid;
    if (u >= xlens[b]) a_ = 0.f;
    alpha[(size_t)b * Uu + u] = a_;
    float s = a_;
    #pragma unroll
    for (int msk = 1; msk < 64; msk <<= 1) s += __shfl_xor(s, msk);
    if (lane == 0) psums[(b << 5) + (u >> 6)] = s;
  }
}

// ---------------- sequential faithful scan (one wave per batch) — unchanged (passed)
__global__ __launch_bounds__(64) void scan_kernel(
    const float* __restrict__ alpha, const float* __restrict__ psums,
    const int* __restrict__ xlens, const int* __restrict__ ylens,
    float* __restrict__ wA, float* __restrict__ wB,
    int* __restrict__ fire_pos, int* __restrict__ nf,
    float* __restrict__ out_sum)
{
  int b = blockIdx.x;
  int lane = threadIdx.x;
  float ps = (lane < 32) ? psums[(b << 5) + lane] : 0.f;
  #pragma unroll
  for (int m = 1; m < 32; m <<= 1) ps += __shfl_xor(ps, m);
  float sa = __shfl(ps, 0);
  float beta = sa / (float)ylens[b] - 1e-4f;
  int xl = xlens[b];
  if (lane == 0) out_sum[b] = sa;

  const float* ab = alpha + (size_t)b * Uu;
  float prev = 0.f;
  int cnt = 0;
  for (int u0 = 0; u0 < Uu; u0 += 64) {
    if (u0 >= xl) break;
    float val = ab[u0 + lane];
    float mywa = 0.f, mywb = 0.f;
    float a_cur = __shfl(val, 0);
    #pragma unroll 4
    for (int i = 0; i < 64; ++i) {
      float a_next = __shfl(val, (i + 1) & 63);
      float nw = prev + a_cur;
      float left = beta - prev;
      float right = nw - beta;
      bool fired = nw >= beta;
      if (lane == i) { mywa = left; mywb = right; }
      if (fired) {
        if (lane == 0) fire_pos[(b << 11) + cnt] = u0 + i;
        ++cnt;
      }
      prev = fired ? right : nw;
      a_cur = a_next;
    }
    wA[(size_t)b * Uu + u0 + lane] = mywa;
    wB[(size_t)b * Uu + u0 + lane] = mywb;
  }
  if (lane == 0) nf[b] = cnt;
}

// ---------------- segmented gather -> h_cif — unchanged (passed)
__global__ __launch_bounds__(512) void gather_kernel(
    const float* __restrict__ xs, const float* __restrict__ wA, const float* __restrict__ wB,
    const int* __restrict__ fire_pos, const int* __restrict__ nf,
    float* __restrict__ out, int umax)
{
  int t = blockIdx.x, b = blockIdx.y;
  int tid = threadIdx.x;
  float* o = out + ((size_t)b * umax + t) * Dd;
  int n = nf[b];
  if (t >= n) { o[tid] = 0.f; return; }
  int start = (t == 0) ? 0 : fire_pos[(b << 11) + t - 1];
  int end = fire_pos[(b << 11) + t];
  const float* xb = xs + (size_t)b * Uu * Dd;
  float acc = 0.f;
  for (int u = start; u <= end; ++u) {
    float w = (t > 0 && u == start) ? wB[(size_t)b * Uu + u] : wA[(size_t)b * Uu + u];
    acc += w * xb[(size_t)u * Dd + tid];
  }
  o[tid] = acc;
}

extern "C" void kernel_launch(void* const* d_in, const int* in_sizes, int n_in,
                              void* d_out, int out_size, void* d_ws, size_t ws_size,
                              hipStream_t stream) {
  const float* xs     = (const float*)d_in[0];
  const int*   xlens  = (const int*)d_in[1];
  const int*   ylens  = (const int*)d_in[2];
  const float* conv_w = (const float*)d_in[3];
  const float* conv_b = (const float*)d_in[4];
  const float* lin_w  = (const float*)d_in[5];
  const float* lin_b  = (const float*)d_in[6];
  float* out = (float*)d_out;
  int umax = (out_size - Bb) / (Bb * Dd);

  char* ws = (char*)d_ws;
  char*  Bpack    = ws;                                  // 48*106496 = 5,111,808
  float* alpha    = (float*)(ws + 48 * (size_t)STEP_BYTES);
  float* wAv      = alpha + BU;
  float* wBv      = wAv + BU;
  int*   fire_pos = (int*)(wBv + BU);
  float* psums    = (float*)(fire_pos + BU);
  int*   nf       = (int*)(psums + 512);

  pack_b_kernel<<<(48 * 2048) / 256, 256, 0, stream>>>(conv_w, Bpack);
  conv_mfma_kernel<<<256, 512, 0, stream>>>(xs, Bpack, conv_b, lin_w, lin_b, xlens,
                                            alpha, psums);
  scan_kernel<<<Bb, 64, 0, stream>>>(alpha, psums, xlens, ylens, wAv, wBv, fire_pos, nf,
                                     out + (size_t)Bb * umax * Dd);
  if (umax > 0)
    gather_kernel<<<dim3(umax, Bb), 512, 0, stream>>>(xs, wAv, wBv, fire_pos, nf, out, umax);
}